// Round 13
// baseline (616.049 us; speedup 1.0000x reference)
//
#include <hip/hip_runtime.h>
#include <cstdint>
#include <cstddef>

#define NROWS 16384
#define KDIM  16384
#define EPSF  1e-7f
#define MINN  1e-15f
#define MAXN  1e6f
#define KSPLIT 4
#define KRANGE (KDIM/KSPLIT)   /* 4096 */
#define BM    64               /* rows per block */
#define BK    64               /* K elems per step */
#define NSTEP (KRANGE/BK)      /* 64 */
#define NRB   (NROWS/BM)       /* 256 */
#define APGS  528              /* A page: 64 rows*8B + 16B pad */
#define BPGS  520              /* B page: 64 cols*8B + 8B pad */
#define ABUF  (8*APGS)         /* 4224 */
#define BBUF  (8*BPGS)         /* 4160 */

typedef __attribute__((ext_vector_type(16))) float f32x16;
typedef long long i64;
typedef unsigned long long u64;
typedef unsigned int uint;

__device__ __forceinline__ float wredsum(float v){
  v += __shfl_xor(v, 1);
  v += __shfl_xor(v, 2);
  v += __shfl_xor(v, 4);
  v += __shfl_xor(v, 8);
  v += __shfl_xor(v, 16);
  v += __shfl_xor(v, 32);
  return v;
}

// ---- ub = logmap0(proj(expmap0(proj_tan0(b)))) for b1 (wave0) and b2 (wave1)
__global__ __launch_bounds__(128) void k_bias(const float* __restrict__ b1,
                                              const float* __restrict__ b2,
                                              float* __restrict__ ub){
  int w = threadIdx.x >> 6, l = threadIdx.x & 63;
  const float* b = w ? b2 : b1;
  float bv = b[l];
  float tb = l ? bv : 0.f;
  float s  = wredsum(tb*tb);
  float xn = fmaxf(sqrtf(s), MINN);
  float sc = sinhf(xn)/xn;
  float e  = sc*tb;
  float s2 = wredsum(e*e);
  float x0 = sqrtf(fmaxf(1.f+s2, EPSF));
  float yn = fmaxf(sqrtf(s2), MINN);
  float th = fmaxf(x0, 1.f+EPSF);
  float u  = l ? acoshf(th)*e/yn : 0.f;
  ub[w*64 + l] = u;
}

// ---- adj f32 -> fp8 e4m3 copy + exact f32 rowsum -> rinv (wave-per-row, 4x ILP)
__global__ __launch_bounds__(256) void k_cvt(const float* __restrict__ adj,
                                             uint* __restrict__ adjF8,
                                             float* __restrict__ rinv){
  int tid  = threadIdx.x;
  int lane = tid & 63;
  int row  = blockIdx.x*4 + (tid >> 6);
  const float4* src = (const float4*)(adj + (size_t)row*KDIM);
  uint* dst = adjF8 + (size_t)row*(KDIM/4);
  float rs = 0.f;
  for(int it = 0; it < 16; it++){              // 16 x (4 float4/lane)
    float4 v0 = src[(it*4+0)*64 + lane];
    float4 v1 = src[(it*4+1)*64 + lane];
    float4 v2 = src[(it*4+2)*64 + lane];
    float4 v3 = src[(it*4+3)*64 + lane];
    rs += (v0.x+v0.y)+(v0.z+v0.w) + (v1.x+v1.y)+(v1.z+v1.w)
        + (v2.x+v2.y)+(v2.z+v2.w) + (v3.x+v3.y)+(v3.z+v3.w);
    uint p0 = __builtin_amdgcn_cvt_pk_fp8_f32(v0.x, v0.y, 0u, false);
    p0 = __builtin_amdgcn_cvt_pk_fp8_f32(v0.z, v0.w, p0, true);
    uint p1 = __builtin_amdgcn_cvt_pk_fp8_f32(v1.x, v1.y, 0u, false);
    p1 = __builtin_amdgcn_cvt_pk_fp8_f32(v1.z, v1.w, p1, true);
    uint p2 = __builtin_amdgcn_cvt_pk_fp8_f32(v2.x, v2.y, 0u, false);
    p2 = __builtin_amdgcn_cvt_pk_fp8_f32(v2.z, v2.w, p2, true);
    uint p3 = __builtin_amdgcn_cvt_pk_fp8_f32(v3.x, v3.y, 0u, false);
    p3 = __builtin_amdgcn_cvt_pk_fp8_f32(v3.z, v3.w, p3, true);
    dst[(it*4+0)*64 + lane] = p0;
    dst[(it*4+1)*64 + lane] = p1;
    dst[(it*4+2)*64 + lane] = p2;
    dst[(it*4+3)*64 + lane] = p3;
  }
  rs = wredsum(rs);
  if (lane == 0) rinv[row] = (rs != 0.f) ? 1.f/rs : 0.f;
}

// ---- device helper: the linear+mobius chain (input v already on-manifold or raw)
// MODE 0: v = raw x row;  MODE 1: v = h row (on hyperboloid)
template<int MODE>
__device__ __forceinline__ float lin_chain(float v, int lane,
                                           const float* __restrict__ Wt,
                                           const float* __restrict__ ub){
  float lx;
  if (MODE == 0){
    float t  = lane ? v : 0.f;
    float s  = wredsum(t*t);
    float tn = fmaxf(sqrtf(s), MINN);
    float sc = sinhf(tn)/tn;
    float e  = sc*t;
    float s2 = wredsum(e*e);
    float x0 = sqrtf(fmaxf(1.f+s2, EPSF));
    float yn = fmaxf(sqrtf(s2), MINN);
    float th = fmaxf(x0, 1.f+EPSF);
    lx = lane ? acoshf(th)*e/yn : 0.f;
  } else {
    float t  = lane ? v : 0.f;
    float s2 = wredsum(t*t);
    float x0 = __shfl(v, 0);
    float yn = fmaxf(sqrtf(s2), MINN);
    float th = fmaxf(x0, 1.f+EPSF);
    lx = lane ? acoshf(th)*t/yn : 0.f;
  }
  float mv = 0.f;
  #pragma unroll
  for(int k = 0; k < 64; k++){
    mv = fmaf(__shfl(lx, k), Wt[k*65 + lane], mv);
  }
  float u  = lane ? mv : 0.f;
  float s  = wredsum(u*u);
  float un = fmaxf(sqrtf(s), MINN);
  float sc = sinhf(un)/un;
  float e  = sc*u;
  float s2 = wredsum(e*e);
  float r0 = sqrtf(fmaxf(1.f+s2, EPSF));
  float ubt   = lane ? ub[lane] : 0.f;
  float yn    = fmaxf(sqrtf(s2), MINN);
  float yhat  = e/yn;
  float alpha = wredsum(yhat*ubt);
  float w     = ubt - alpha*(1.f - r0)*yhat;
  float ux    = wredsum(e*w);
  float v0    = ux / fmaxf(r0, EPSF);
  float md    = wredsum(w*w) - v0*v0;
  float normu = fminf(sqrtf(fmaxf(md, EPSF)), MAXN);
  float th2   = fmaxf(normu, MINN);
  float ch    = coshf(th2);
  float shq   = sinhf(th2)/th2;
  float ov    = ch*(lane ? e : r0) + shq*(lane ? w : v0);
  float ot    = lane ? ov : 0.f;
  float s3    = wredsum(ot*ot);
  float o0    = sqrtf(fmaxf(1.f+s3, EPSF));
  float yn2 = fmaxf(sqrtf(s3), MINN);
  float th3 = fmaxf(o0, 1.f+EPSF);
  return lane ? acoshf(th3)*ot/yn2 : 0.f;
}

// ---- shared epilogue: transpose LDS g-tile (64x65 f32) -> gF8T fp8
__device__ __forceinline__ void tr_out(const float (*gt)[65], int tid, int blk,
                                       uint* __restrict__ gF8T){
  int n   = tid >> 2;
  int seg = tid & 3;
  int s16 = seg*16;
  uint4 p;
  p.x = __builtin_amdgcn_cvt_pk_fp8_f32(gt[s16+ 0][n], gt[s16+ 1][n], 0u, false);
  p.x = __builtin_amdgcn_cvt_pk_fp8_f32(gt[s16+ 2][n], gt[s16+ 3][n], p.x, true);
  p.y = __builtin_amdgcn_cvt_pk_fp8_f32(gt[s16+ 4][n], gt[s16+ 5][n], 0u, false);
  p.y = __builtin_amdgcn_cvt_pk_fp8_f32(gt[s16+ 6][n], gt[s16+ 7][n], p.y, true);
  p.z = __builtin_amdgcn_cvt_pk_fp8_f32(gt[s16+ 8][n], gt[s16+ 9][n], 0u, false);
  p.z = __builtin_amdgcn_cvt_pk_fp8_f32(gt[s16+10][n], gt[s16+11][n], p.z, true);
  p.w = __builtin_amdgcn_cvt_pk_fp8_f32(gt[s16+12][n], gt[s16+13][n], 0u, false);
  p.w = __builtin_amdgcn_cvt_pk_fp8_f32(gt[s16+14][n], gt[s16+15][n], p.w, true);
  uint4* dst = (uint4*)gF8T + (size_t)n*(KDIM/16) + blk*4 + seg;
  *dst = p;
}

// ---- fused layer-1 front: linear<0> + transpose + fp8  (x -> gF8T)
__global__ __launch_bounds__(256) void k_lin0(const float* __restrict__ x,
                                              const float* __restrict__ W,
                                              const float* __restrict__ ub,
                                              uint* __restrict__ gF8T){
  __shared__ float Wt[64*65];
  __shared__ float gt[64][65];
  int tid = threadIdx.x;
  for(int idx = tid; idx < 4096; idx += 256){
    int j = idx >> 6, k = idx & 63;
    Wt[k*65 + j] = W[idx];
  }
  __syncthreads();
  int lane = tid & 63, w = tid >> 6;
  int rbase = blockIdx.x*64 + w*16;
  for(int rr = 0; rr < 16; rr++){
    float v = x[(size_t)(rbase + rr)*64 + lane];
    gt[w*16 + rr][lane] = lin_chain<0>(v, lane, Wt, ub);
  }
  __syncthreads();
  tr_out(gt, tid, blockIdx.x, gF8T);
}

// ---- fused mid: split-K reduce + postagg -> h1, then linear<1> + transpose + fp8 -> gF8T
__global__ __launch_bounds__(256) void k_mid(const float* __restrict__ pagg,
                                             const float* __restrict__ rinv,
                                             const float* __restrict__ W,
                                             const float* __restrict__ ub,
                                             float* __restrict__ h,
                                             uint* __restrict__ gF8T){
  __shared__ float Wt[64*65];
  __shared__ float gt[64][65];
  int tid = threadIdx.x;
  for(int idx = tid; idx < 4096; idx += 256){
    int j = idx >> 6, k = idx & 63;
    Wt[k*65 + j] = W[idx];
  }
  __syncthreads();
  int lane = tid & 63, w = tid >> 6;
  int rbase = blockIdx.x*64 + w*16;
  for(int rr = 0; rr < 16; rr++){
    int row = rbase + rr;
    float s = 0.f;
    #pragma unroll
    for(int ks = 0; ks < KSPLIT; ks++) s += pagg[(size_t)ks*NROWS*64 + (size_t)row*64 + lane];
    float a  = s * rinv[row];
    float at = lane ? a : 0.f;
    float ss = wredsum(at*at);
    float un = fmaxf(sqrtf(ss), MINN);
    float sc = sinhf(un)/un;
    float e  = sc*at;
    float s2 = wredsum(e*e);
    float x0 = sqrtf(fmaxf(1.f+s2, EPSF));
    float yn = fmaxf(sqrtf(s2), MINN);
    float th = fmaxf(x0, 1.f+EPSF);
    float lt = lane ? acoshf(th)*e/yn : 0.f;
    float rl = fmaxf(lt, 0.f);
    float s3 = wredsum(rl*rl);
    float rn = fmaxf(sqrtf(s3), MINN);
    float sc2= sinhf(rn)/rn;
    float e2 = sc2*rl;
    float s4 = wredsum(e2*e2);
    float h0 = sqrtf(fmaxf(1.f+s4, EPSF));
    float hv = lane ? e2 : h0;
    h[(size_t)row*64 + lane] = hv;
    gt[w*16 + rr][lane] = lin_chain<1>(hv, lane, Wt, ub);
  }
  __syncthreads();
  tr_out(gt, tid, blockIdx.x, gF8T);
}

// ---- fp8 32x32x16 MFMA split-K matmul: A and B LDS-staged (R11-proven), KSPLIT=4
__global__ __launch_bounds__(256) void k_matmul(const unsigned char* __restrict__ adjF8,
                                                const unsigned char* __restrict__ gF8T,
                                                float* __restrict__ pagg){
  __shared__ __align__(16) char Alds[2*ABUF];
  __shared__ __align__(16) char Blds[2*BBUF];
  int tid  = threadIdx.x;
  int lane = tid & 63, w = tid >> 6;
  int rb   = blockIdx.x;               // rb in LOW grid bits
  int ks   = blockIdx.y;
  int row0 = rb*BM;
  size_t k0 = (size_t)ks * KRANGE;

  int sr   = tid >> 2;
  int sseg = tid & 3;
  const uint4* ap = (const uint4*)(adjF8 + (size_t)(row0 + sr)*KDIM + k0 + sseg*16);
  int AwOff0 = (2*sseg    )*APGS + sr*8;
  int AwOff1 = (2*sseg + 1)*APGS + sr*8;

  int sc  = tid >> 2;
  int skq = tid & 3;
  const uint4* bsp = (const uint4*)(gF8T + (size_t)sc*KDIM + k0 + skq*16);
  int BwOff0 = (2*skq    )*BPGS + sc*8;
  int BwOff1 = (2*skq + 1)*BPGS + sc*8;

  int wm = w >> 1, wn = w & 1;
  int lr = lane & 31, lh = lane >> 5;
  int ArdOff = lh*APGS + (wm*32 + lr)*8;
  int BrdOff = lh*BPGS + (wn*32 + lr)*8;

  f32x16 acc;
  #pragma unroll
  for(int q = 0; q < 16; q++) acc[q] = 0.f;

  uint4 aR, aN, bR, bN;

  aR = ap[0];
  bR = bsp[0];
  {
    union { uint4 v; u64 q[2]; } ua; ua.v = aR;
    *(u64*)(Alds + AwOff0) = ua.q[0];
    *(u64*)(Alds + AwOff1) = ua.q[1];
    union { uint4 v; u64 q[2]; } ub_; ub_.v = bR;
    *(u64*)(Blds + BwOff0) = ub_.q[0];
    *(u64*)(Blds + BwOff1) = ub_.q[1];
  }
  aR = ap[4];
  bR = bsp[4];
  __syncthreads();

  for (int i = 0; i < NSTEP; i++){
    const char* Ab = Alds + (i & 1)*ABUF;
    const char* Bb = Blds + (i & 1)*BBUF;
    i64 af0 = *(const i64*)(Ab + ArdOff);
    i64 af1 = *(const i64*)(Ab + ArdOff + 2*APGS);
    i64 af2 = *(const i64*)(Ab + ArdOff + 4*APGS);
    i64 af3 = *(const i64*)(Ab + ArdOff + 6*APGS);
    i64 bf0 = *(const i64*)(Bb + BrdOff);
    i64 bf1 = *(const i64*)(Bb + BrdOff + 2*BPGS);
    i64 bf2 = *(const i64*)(Bb + BrdOff + 4*BPGS);
    i64 bf3 = *(const i64*)(Bb + BrdOff + 6*BPGS);
    if (i + 2 < NSTEP){
      aN = ap[(i+2)*4];
      bN = bsp[(i+2)*4];
    }
    acc = __builtin_amdgcn_mfma_f32_32x32x16_fp8_fp8(af0, bf0, acc, 0, 0, 0);
    acc = __builtin_amdgcn_mfma_f32_32x32x16_fp8_fp8(af1, bf1, acc, 0, 0, 0);
    acc = __builtin_amdgcn_mfma_f32_32x32x16_fp8_fp8(af2, bf2, acc, 0, 0, 0);
    acc = __builtin_amdgcn_mfma_f32_32x32x16_fp8_fp8(af3, bf3, acc, 0, 0, 0);
    if (i + 1 < NSTEP){
      char* Aw = Alds + ((i+1) & 1)*ABUF;
      char* Bw = Blds + ((i+1) & 1)*BBUF;
      union { uint4 v; u64 q[2]; } ua; ua.v = aR;
      *(u64*)(Aw + AwOff0) = ua.q[0];
      *(u64*)(Aw + AwOff1) = ua.q[1];
      union { uint4 v; u64 q[2]; } ub_; ub_.v = bR;
      *(u64*)(Bw + BwOff0) = ub_.q[0];
      *(u64*)(Bw + BwOff1) = ub_.q[1];
    }
    aR = aN; bR = bN;
    __syncthreads();
  }

  float* ob = pagg + ((size_t)ks*NROWS + row0 + wm*32)*64 + wn*32;
  #pragma unroll
  for(int q = 0; q < 16; q++){
    int rl = (q & 3) + 8*(q >> 2) + 4*lh;
    ob[(size_t)rl*64 + lr] = acc[q];
  }
}

// ---- layer-2 tail: split-K reduce + postagg chain -> h2
__global__ __launch_bounds__(256) void k_post2(const float* __restrict__ pagg,
                                               const float* __restrict__ rinv,
                                               float* __restrict__ h){
  int tid = threadIdx.x; int lane = tid & 63;
  int row = blockIdx.x*4 + (tid >> 6);
  float s = 0.f;
  #pragma unroll
  for(int ks = 0; ks < KSPLIT; ks++) s += pagg[(size_t)ks*NROWS*64 + (size_t)row*64 + lane];
  float a  = s * rinv[row];
  float at = lane ? a : 0.f;
  float ss = wredsum(at*at);
  float un = fmaxf(sqrtf(ss), MINN);
  float sc = sinhf(un)/un;
  float e  = sc*at;
  float s2 = wredsum(e*e);
  float x0 = sqrtf(fmaxf(1.f+s2, EPSF));
  float yn = fmaxf(sqrtf(s2), MINN);
  float th = fmaxf(x0, 1.f+EPSF);
  float lt = lane ? acoshf(th)*e/yn : 0.f;
  float rl = fmaxf(lt, 0.f);
  float s3 = wredsum(rl*rl);
  float rn = fmaxf(sqrtf(s3), MINN);
  float sc2= sinhf(rn)/rn;
  float e2 = sc2*rl;
  float s4 = wredsum(e2*e2);
  float h0 = sqrtf(fmaxf(1.f+s4, EPSF));
  h[(size_t)row*64 + lane] = lane ? e2 : h0;
}

extern "C" void kernel_launch(void* const* d_in, const int* in_sizes, int n_in,
                              void* d_out, int out_size, void* d_ws, size_t ws_size,
                              hipStream_t stream){
  const float* x   = (const float*)d_in[0];
  const float* adj = (const float*)d_in[1];
  const float* W1  = (const float*)d_in[2];
  const float* b1  = (const float*)d_in[3];
  const float* W2  = (const float*)d_in[4];
  const float* b2  = (const float*)d_in[5];
  float* out = (float*)d_out;
  float* h1  = out;
  float* h2  = out + (size_t)NROWS*64;

  float* wsf   = (float*)d_ws;
  float* pagg  = wsf;                              // KSPLIT*N*64 f32 (16.8 MB)
  float* rinv  = pagg  + (size_t)KSPLIT*NROWS*64;  // N
  float* ubs   = rinv  + NROWS;                    // 128
  uint*  gF8T  = (uint*)(ubs + 128);               // 64*N fp8 (1 MB)
  uint*  adjF8 = gF8T + (size_t)64*KDIM/4;         // N*N fp8 (268 MB)

  dim3 gm(NRB, KSPLIT);                            // rb in LOW bits

  k_bias<<<1, 128, 0, stream>>>(b1, b2, ubs);
  k_cvt<<<NROWS/4, 256, 0, stream>>>(adj, adjF8, rinv);
  // layer 1
  k_lin0<<<NROWS/64, 256, 0, stream>>>(x, W1, ubs, gF8T);
  k_matmul<<<gm, 256, 0, stream>>>((const unsigned char*)adjF8, (const unsigned char*)gF8T, pagg);
  // mid: post1 + linear2 + transpose
  k_mid<<<NROWS/64, 256, 0, stream>>>(pagg, rinv, W2, ubs + 64, h1, gF8T);
  // layer 2
  k_matmul<<<gm, 256, 0, stream>>>((const unsigned char*)adjF8, (const unsigned char*)gF8T, pagg);
  k_post2<<<NROWS/4, 256, 0, stream>>>(pagg, rinv, h2);
}

// Round 15
// 508.376 us; speedup vs baseline: 1.2118x; 1.2118x over previous
//
#include <hip/hip_runtime.h>
#include <cstdint>
#include <cstddef>

#define NROWS 16384
#define KDIM  16384
#define EPSF  1e-7f
#define MINN  1e-15f
#define MAXN  1e6f
#define KSPLIT 8
#define KRANGE (KDIM/KSPLIT)   /* 2048 */
#define BM    64               /* rows per block */
#define BK    64               /* K bytes per step (fp8) */
#define NSTEP (KRANGE/BK)      /* 32 */
#define APGS  528              /* A page: 64 rows*8B + 16B pad */
#define BPGS  520              /* B page: 64 cols*8B + 8B pad */
#define ABUF  (8*APGS)         /* 4224 */
#define BBUF  (8*BPGS)         /* 4160 */

typedef __attribute__((ext_vector_type(16))) float f32x16;
typedef __attribute__((ext_vector_type(4)))  float f32x4v;   // native vec for nt-load
typedef long long i64;
typedef unsigned long long u64;
typedef unsigned int uint;

__device__ __forceinline__ float wredsum(float v){
  v += __shfl_xor(v, 1);
  v += __shfl_xor(v, 2);
  v += __shfl_xor(v, 4);
  v += __shfl_xor(v, 8);
  v += __shfl_xor(v, 16);
  v += __shfl_xor(v, 32);
  return v;
}

// ---- ub = logmap0(proj(expmap0(proj_tan0(b)))) for b1 (wave0) and b2 (wave1)
__global__ __launch_bounds__(128) void k_bias(const float* __restrict__ b1,
                                              const float* __restrict__ b2,
                                              float* __restrict__ ub){
  int w = threadIdx.x >> 6, l = threadIdx.x & 63;
  const float* b = w ? b2 : b1;
  float bv = b[l];
  float tb = l ? bv : 0.f;
  float s  = wredsum(tb*tb);
  float xn = fmaxf(sqrtf(s), MINN);
  float sc = sinhf(xn)/xn;
  float e  = sc*tb;
  float s2 = wredsum(e*e);
  float x0 = sqrtf(fmaxf(1.f+s2, EPSF));
  float yn = fmaxf(sqrtf(s2), MINN);
  float th = fmaxf(x0, 1.f+EPSF);
  float u  = l ? acoshf(th)*e/yn : 0.f;
  ub[w*64 + l] = u;
}

// ---- adj f32 -> fp8 e4m3 copy + exact f32 rowsum -> rinv  (wave-per-row stream)
// NT loads: adj has zero reuse; no-allocate keeps the freshly-written adjF8
// (exactly 256 MiB = L3 size) resident in Infinity Cache for both matmuls.
__global__ __launch_bounds__(256) void k_cvt(const float* __restrict__ adj,
                                             uint* __restrict__ adjF8,
                                             float* __restrict__ rinv){
  int tid  = threadIdx.x;
  int lane = tid & 63;
  int row  = blockIdx.x*4 + (tid >> 6);
  const f32x4v* src = (const f32x4v*)(adj + (size_t)row*KDIM);
  uint* dst = adjF8 + (size_t)row*(KDIM/4);
  float rs = 0.f;
  #pragma unroll 8
  for(int it = 0; it < KDIM/256; it++){        // 64 iters x (64 lanes x float4)
    f32x4v v = __builtin_nontemporal_load(src + it*64 + lane);
    rs += (v.x + v.y) + (v.z + v.w);
    uint p = __builtin_amdgcn_cvt_pk_fp8_f32(v.x, v.y, 0u, false);
    p = __builtin_amdgcn_cvt_pk_fp8_f32(v.z, v.w, p, true);
    dst[it*64 + lane] = p;
  }
  rs = wredsum(rs);
  if (lane == 0) rinv[row] = (rs != 0.f) ? 1.f/rs : 0.f;
}

// ---- per-row linear + mobius bias chain -> g
template<int MODE>
__global__ __launch_bounds__(256) void k_linear(const float* __restrict__ in,
                                                const float* __restrict__ W,
                                                const float* __restrict__ ub,
                                                float* __restrict__ g){
  __shared__ float Wt[64*65];
  int tid = threadIdx.x;
  for(int idx = tid; idx < 4096; idx += 256){
    int j = idx >> 6, k = idx & 63;
    Wt[k*65 + j] = W[idx];
  }
  __syncthreads();
  int lane = tid & 63;
  int row  = blockIdx.x*4 + (tid >> 6);
  float v = in[(size_t)row*64 + lane];
  float lx;
  if (MODE == 0){
    float t  = lane ? v : 0.f;
    float s  = wredsum(t*t);
    float tn = fmaxf(sqrtf(s), MINN);
    float sc = sinhf(tn)/tn;
    float e  = sc*t;
    float s2 = wredsum(e*e);
    float x0 = sqrtf(fmaxf(1.f+s2, EPSF));
    float yn = fmaxf(sqrtf(s2), MINN);
    float th = fmaxf(x0, 1.f+EPSF);
    lx = lane ? acoshf(th)*e/yn : 0.f;
  } else {
    float t  = lane ? v : 0.f;
    float s2 = wredsum(t*t);
    float x0 = __shfl(v, 0);
    float yn = fmaxf(sqrtf(s2), MINN);
    float th = fmaxf(x0, 1.f+EPSF);
    lx = lane ? acoshf(th)*t/yn : 0.f;
  }
  float mv = 0.f;
  #pragma unroll
  for(int k = 0; k < 64; k++){
    mv = fmaf(__shfl(lx, k), Wt[k*65 + lane], mv);
  }
  float u  = lane ? mv : 0.f;
  float s  = wredsum(u*u);
  float un = fmaxf(sqrtf(s), MINN);
  float sc = sinhf(un)/un;
  float e  = sc*u;
  float s2 = wredsum(e*e);
  float r0 = sqrtf(fmaxf(1.f+s2, EPSF));
  float ubt   = lane ? ub[lane] : 0.f;
  float yn    = fmaxf(sqrtf(s2), MINN);
  float yhat  = e/yn;
  float alpha = wredsum(yhat*ubt);
  float w     = ubt - alpha*(1.f - r0)*yhat;
  float ux    = wredsum(e*w);
  float v0    = ux / fmaxf(r0, EPSF);
  float md    = wredsum(w*w) - v0*v0;
  float normu = fminf(sqrtf(fmaxf(md, EPSF)), MAXN);
  float th2   = fmaxf(normu, MINN);
  float ch    = coshf(th2);
  float shq   = sinhf(th2)/th2;
  float ov    = ch*(lane ? e : r0) + shq*(lane ? w : v0);
  float ot    = lane ? ov : 0.f;
  float s3    = wredsum(ot*ot);
  float o0    = sqrtf(fmaxf(1.f+s3, EPSF));
  float yn2 = fmaxf(sqrtf(s3), MINN);
  float th3 = fmaxf(o0, 1.f+EPSF);
  float gv  = lane ? acoshf(th3)*ot/yn2 : 0.f;
  g[(size_t)row*64 + lane] = gv;
}

// ---- transpose + fp8 convert: g[N][64] f32 -> gF8T[64][N] fp8
__global__ __launch_bounds__(256) void k_trf8(const float* __restrict__ g,
                                              uint* __restrict__ gF8T){
  __shared__ float t[64][65];
  int tid = threadIdx.x;
  int b   = blockIdx.x;
  int r   = tid >> 2;
  int c0  = (tid & 3)*16;
  const float* src = g + ((size_t)b*64 + r)*64 + c0;
  #pragma unroll
  for(int i = 0; i < 4; i++){
    float4 v = *(const float4*)(src + i*4);
    t[r][c0 + i*4 + 0] = v.x; t[r][c0 + i*4 + 1] = v.y;
    t[r][c0 + i*4 + 2] = v.z; t[r][c0 + i*4 + 3] = v.w;
  }
  __syncthreads();
  int n   = tid >> 2;
  int seg = tid & 3;
  int s16 = seg*16;
  uint4 p;
  p.x = __builtin_amdgcn_cvt_pk_fp8_f32(t[s16+ 0][n], t[s16+ 1][n], 0u, false);
  p.x = __builtin_amdgcn_cvt_pk_fp8_f32(t[s16+ 2][n], t[s16+ 3][n], p.x, true);
  p.y = __builtin_amdgcn_cvt_pk_fp8_f32(t[s16+ 4][n], t[s16+ 5][n], 0u, false);
  p.y = __builtin_amdgcn_cvt_pk_fp8_f32(t[s16+ 6][n], t[s16+ 7][n], p.y, true);
  p.z = __builtin_amdgcn_cvt_pk_fp8_f32(t[s16+ 8][n], t[s16+ 9][n], 0u, false);
  p.z = __builtin_amdgcn_cvt_pk_fp8_f32(t[s16+10][n], t[s16+11][n], p.z, true);
  p.w = __builtin_amdgcn_cvt_pk_fp8_f32(t[s16+12][n], t[s16+13][n], 0u, false);
  p.w = __builtin_amdgcn_cvt_pk_fp8_f32(t[s16+14][n], t[s16+15][n], p.w, true);
  uint4* dst = (uint4*)gF8T + (size_t)n*(KDIM/16) + b*4 + seg;
  *dst = p;
}

// ---- fp8 32x32x16 MFMA split-K matmul: A and B both LDS-staged (dbuf, 1 barrier/step)
__global__ __launch_bounds__(256) void k_matmul(const unsigned char* __restrict__ adjF8,
                                                const unsigned char* __restrict__ gF8T,
                                                float* __restrict__ pagg){
  __shared__ __align__(16) char Alds[2*ABUF];   // 8.4 KB
  __shared__ __align__(16) char Blds[2*BBUF];   // 8.3 KB
  int tid  = threadIdx.x;
  int lane = tid & 63, w = tid >> 6;
  int rb   = blockIdx.x;               // rb in LOW grid bits
  int ks   = blockIdx.y;
  int row0 = rb*BM;
  size_t k0 = (size_t)ks * KRANGE;

  // A staging: thread -> (row sr, 16B k-seg sseg); coalesced uint4
  int sr   = tid >> 2;                 // 0..63
  int sseg = tid & 3;                  // 0..3
  const uint4* ap = (const uint4*)(adjF8 + (size_t)(row0 + sr)*KDIM + k0 + sseg*16);
  int AwOff0 = (2*sseg    )*APGS + sr*8;
  int AwOff1 = (2*sseg + 1)*APGS + sr*8;

  // B staging: thread -> (col sc, 16B k-seg skq); 64B full-line granule per col
  int sc  = tid >> 2;                  // 0..63 (col)
  int skq = tid & 3;                   // 0..3
  const uint4* bsp = (const uint4*)(gF8T + (size_t)sc*KDIM + k0 + skq*16);
  int BwOff0 = (2*skq    )*BPGS + sc*8;
  int BwOff1 = (2*skq + 1)*BPGS + sc*8;

  // compute role: wave (wm,wn) -> rows wm*32..+32, cols wn*32..+32
  int wm = w >> 1, wn = w & 1;
  int lr = lane & 31, lh = lane >> 5;
  int ArdOff = lh*APGS + (wm*32 + lr)*8;         // chunk m adds 2m*APGS
  int BrdOff = lh*BPGS + (wn*32 + lr)*8;         // chunk m adds 2m*BPGS

  f32x16 acc;
  #pragma unroll
  for(int q = 0; q < 16; q++) acc[q] = 0.f;

  uint4 aR, aN, bR, bN;

  // prologue: stage step 0; preload step 1
  aR = ap[0];
  bR = bsp[0];
  {
    union { uint4 v; u64 q[2]; } ua; ua.v = aR;
    *(u64*)(Alds + AwOff0) = ua.q[0];
    *(u64*)(Alds + AwOff1) = ua.q[1];
    union { uint4 v; u64 q[2]; } ub_; ub_.v = bR;
    *(u64*)(Blds + BwOff0) = ub_.q[0];
    *(u64*)(Blds + BwOff1) = ub_.q[1];
  }
  aR = ap[4];                                    // step stride = 4 uint4 (64B)
  bR = bsp[4];
  __syncthreads();

  for (int i = 0; i < NSTEP; i++){
    const char* Ab = Alds + (i & 1)*ABUF;
    const char* Bb = Blds + (i & 1)*BBUF;
    i64 af0 = *(const i64*)(Ab + ArdOff);
    i64 af1 = *(const i64*)(Ab + ArdOff + 2*APGS);
    i64 af2 = *(const i64*)(Ab + ArdOff + 4*APGS);
    i64 af3 = *(const i64*)(Ab + ArdOff + 6*APGS);
    i64 bf0 = *(const i64*)(Bb + BrdOff);
    i64 bf1 = *(const i64*)(Bb + BrdOff + 2*BPGS);
    i64 bf2 = *(const i64*)(Bb + BrdOff + 4*BPGS);
    i64 bf3 = *(const i64*)(Bb + BrdOff + 6*BPGS);
    if (i + 2 < NSTEP){
      aN = ap[(i+2)*4];
      bN = bsp[(i+2)*4];
    }
    acc = __builtin_amdgcn_mfma_f32_32x32x16_fp8_fp8(af0, bf0, acc, 0, 0, 0);
    acc = __builtin_amdgcn_mfma_f32_32x32x16_fp8_fp8(af1, bf1, acc, 0, 0, 0);
    acc = __builtin_amdgcn_mfma_f32_32x32x16_fp8_fp8(af2, bf2, acc, 0, 0, 0);
    acc = __builtin_amdgcn_mfma_f32_32x32x16_fp8_fp8(af3, bf3, acc, 0, 0, 0);
    if (i + 1 < NSTEP){
      char* Aw = Alds + ((i+1) & 1)*ABUF;
      char* Bw = Blds + ((i+1) & 1)*BBUF;
      union { uint4 v; u64 q[2]; } ua; ua.v = aR;
      *(u64*)(Aw + AwOff0) = ua.q[0];
      *(u64*)(Aw + AwOff1) = ua.q[1];
      union { uint4 v; u64 q[2]; } ub_; ub_.v = bR;
      *(u64*)(Bw + BwOff0) = ub_.q[0];
      *(u64*)(Bw + BwOff1) = ub_.q[1];
    }
    aR = aN; bR = bN;
    __syncthreads();
  }

  // C write: 32x32 D layout (m74): col = lane&31, row = (q&3) + 8*(q>>2) + 4*(lane>>5)
  float* ob = pagg + ((size_t)ks*NROWS + row0 + wm*32)*64 + wn*32;
  #pragma unroll
  for(int q = 0; q < 16; q++){
    int rl = (q & 3) + 8*(q >> 2) + 4*lh;
    ob[(size_t)rl*64 + lr] = acc[q];
  }
}

// ---- fused: split-K reduce + postagg chain -> h (rinv precomputed by k_cvt)
__global__ __launch_bounds__(256) void k_post(const float* __restrict__ pagg,
                                              const float* __restrict__ rinv,
                                              float* __restrict__ h){
  int tid = threadIdx.x; int lane = tid & 63;
  int row = blockIdx.x*4 + (tid >> 6);
  float s = 0.f;
  #pragma unroll
  for(int ks = 0; ks < KSPLIT; ks++) s += pagg[(size_t)ks*NROWS*64 + (size_t)row*64 + lane];
  float a  = s * rinv[row];
  float at = lane ? a : 0.f;
  float ss = wredsum(at*at);
  float un = fmaxf(sqrtf(ss), MINN);
  float sc = sinhf(un)/un;
  float e  = sc*at;
  float s2 = wredsum(e*e);
  float x0 = sqrtf(fmaxf(1.f+s2, EPSF));
  float yn = fmaxf(sqrtf(s2), MINN);
  float th = fmaxf(x0, 1.f+EPSF);
  float lt = lane ? acoshf(th)*e/yn : 0.f;
  float rl = fmaxf(lt, 0.f);
  float s3 = wredsum(rl*rl);
  float rn = fmaxf(sqrtf(s3), MINN);
  float sc2= sinhf(rn)/rn;
  float e2 = sc2*rl;
  float s4 = wredsum(e2*e2);
  float h0 = sqrtf(fmaxf(1.f+s4, EPSF));
  h[(size_t)row*64 + lane] = lane ? e2 : h0;
}

extern "C" void kernel_launch(void* const* d_in, const int* in_sizes, int n_in,
                              void* d_out, int out_size, void* d_ws, size_t ws_size,
                              hipStream_t stream){
  const float* x   = (const float*)d_in[0];
  const float* adj = (const float*)d_in[1];
  const float* W1  = (const float*)d_in[2];
  const float* b1  = (const float*)d_in[3];
  const float* W2  = (const float*)d_in[4];
  const float* b2  = (const float*)d_in[5];
  float* out = (float*)d_out;
  float* h1  = out;
  float* h2  = out + (size_t)NROWS*64;

  float* wsf   = (float*)d_ws;
  float* gbuf  = wsf;                              // N*64 f32 (4 MB)
  float* pagg  = gbuf  + (size_t)NROWS*64;         // KSPLIT*N*64 f32 (33.5 MB)
  float* rinv  = pagg  + (size_t)KSPLIT*NROWS*64;  // N
  float* ubs   = rinv  + NROWS;                    // 128
  uint*  gF8T  = (uint*)(ubs + 128);               // 64*N fp8 (1 MB)
  uint*  adjF8 = gF8T + (size_t)64*KDIM/4;         // N*N fp8 (256 MiB)

  dim3 gm(NROWS/BM, KSPLIT);                       // rb in LOW bits

  k_bias<<<1, 128, 0, stream>>>(b1, b2, ubs);
  k_cvt<<<NROWS/4, 256, 0, stream>>>(adj, adjF8, rinv);
  // layer 1
  k_linear<0><<<NROWS/4, 256, 0, stream>>>(x, W1, ubs, gbuf);
  k_trf8<<<NROWS/64, 256, 0, stream>>>(gbuf, gF8T);
  k_matmul<<<gm, 256, 0, stream>>>((const unsigned char*)adjF8, (const unsigned char*)gF8T, pagg);
  k_post<<<NROWS/4, 256, 0, stream>>>(pagg, rinv, h1);
  // layer 2
  k_linear<1><<<NROWS/4, 256, 0, stream>>>(h1, W2, ubs + 64, gbuf);
  k_trf8<<<NROWS/64, 256, 0, stream>>>(gbuf, gF8T);
  k_matmul<<<gm, 256, 0, stream>>>((const unsigned char*)adjF8, (const unsigned char*)gF8T, pagg);
  k_post<<<NROWS/4, 256, 0, stream>>>(pagg, rinv, h2);
}

// Round 16
// 501.795 us; speedup vs baseline: 1.2277x; 1.0131x over previous
//
#include <hip/hip_runtime.h>
#include <cstdint>
#include <cstddef>

#define NROWS 16384
#define KDIM  16384
#define EPSF  1e-7f
#define MINN  1e-15f
#define MAXN  1e6f
#define KSPLIT 8
#define KRANGE (KDIM/KSPLIT)   /* 2048 */
#define BM    64               /* rows per block */
#define BK    64               /* K bytes per step (fp8) */
#define NSTEP (KRANGE/BK)      /* 32 */
#define APGS  528              /* A page: 64 rows*8B + 16B pad */
#define BPGS  520              /* B page: 64 cols*8B + 8B pad */
#define ABUF  (8*APGS)         /* 4224 */
#define BBUF  (8*BPGS)         /* 4160 */

typedef __attribute__((ext_vector_type(16))) float f32x16;
typedef __attribute__((ext_vector_type(4)))  float f32x4v;   // native vec for nt-load
typedef long long i64;
typedef unsigned long long u64;
typedef unsigned int uint;

__device__ __forceinline__ float wredsum(float v){
  v += __shfl_xor(v, 1);
  v += __shfl_xor(v, 2);
  v += __shfl_xor(v, 4);
  v += __shfl_xor(v, 8);
  v += __shfl_xor(v, 16);
  v += __shfl_xor(v, 32);
  return v;
}

// ---- ub = logmap0(proj(expmap0(proj_tan0(b)))) for b1 (wave0) and b2 (wave1)
__global__ __launch_bounds__(128) void k_bias(const float* __restrict__ b1,
                                              const float* __restrict__ b2,
                                              float* __restrict__ ub){
  int w = threadIdx.x >> 6, l = threadIdx.x & 63;
  const float* b = w ? b2 : b1;
  float bv = b[l];
  float tb = l ? bv : 0.f;
  float s  = wredsum(tb*tb);
  float xn = fmaxf(sqrtf(s), MINN);
  float sc = sinhf(xn)/xn;
  float e  = sc*tb;
  float s2 = wredsum(e*e);
  float x0 = sqrtf(fmaxf(1.f+s2, EPSF));
  float yn = fmaxf(sqrtf(s2), MINN);
  float th = fmaxf(x0, 1.f+EPSF);
  float u  = l ? acoshf(th)*e/yn : 0.f;
  ub[w*64 + l] = u;
}

// ---- adj f32 -> fp8 e4m3 copy + exact f32 rowsum -> rinv  (wave-per-row stream)
// NT loads (no L3 allocate) + per-row K-phase ROTATION: decorrelates the
// 64KB-stride row sweep across DRAM channel units so equal-progress waves
// don't camp on the same channels.
__global__ __launch_bounds__(256) void k_cvt(const float* __restrict__ adj,
                                             uint* __restrict__ adjF8,
                                             float* __restrict__ rinv){
  int tid  = threadIdx.x;
  int lane = tid & 63;
  int row  = blockIdx.x*4 + (tid >> 6);
  int rot  = (row * 17) & 63;                  // 1KB-chunk rotation, covers full row span
  const f32x4v* src = (const f32x4v*)(adj + (size_t)row*KDIM);
  uint* dst = adjF8 + (size_t)row*(KDIM/4);
  float rs = 0.f;
  #pragma unroll 8
  for(int it = 0; it < KDIM/256; it++){        // 64 chunks x (64 lanes x float4)
    int c = (it + rot) & 63;
    f32x4v v = __builtin_nontemporal_load(src + c*64 + lane);
    rs += (v.x + v.y) + (v.z + v.w);
    uint p = __builtin_amdgcn_cvt_pk_fp8_f32(v.x, v.y, 0u, false);
    p = __builtin_amdgcn_cvt_pk_fp8_f32(v.z, v.w, p, true);
    dst[c*64 + lane] = p;
  }
  rs = wredsum(rs);
  if (lane == 0) rinv[row] = (rs != 0.f) ? 1.f/rs : 0.f;
}

// ---- per-row linear + mobius bias chain -> g
template<int MODE>
__global__ __launch_bounds__(256) void k_linear(const float* __restrict__ in,
                                                const float* __restrict__ W,
                                                const float* __restrict__ ub,
                                                float* __restrict__ g){
  __shared__ float Wt[64*65];
  int tid = threadIdx.x;
  for(int idx = tid; idx < 4096; idx += 256){
    int j = idx >> 6, k = idx & 63;
    Wt[k*65 + j] = W[idx];
  }
  __syncthreads();
  int lane = tid & 63;
  int row  = blockIdx.x*4 + (tid >> 6);
  float v = in[(size_t)row*64 + lane];
  float lx;
  if (MODE == 0){
    float t  = lane ? v : 0.f;
    float s  = wredsum(t*t);
    float tn = fmaxf(sqrtf(s), MINN);
    float sc = sinhf(tn)/tn;
    float e  = sc*t;
    float s2 = wredsum(e*e);
    float x0 = sqrtf(fmaxf(1.f+s2, EPSF));
    float yn = fmaxf(sqrtf(s2), MINN);
    float th = fmaxf(x0, 1.f+EPSF);
    lx = lane ? acoshf(th)*e/yn : 0.f;
  } else {
    float t  = lane ? v : 0.f;
    float s2 = wredsum(t*t);
    float x0 = __shfl(v, 0);
    float yn = fmaxf(sqrtf(s2), MINN);
    float th = fmaxf(x0, 1.f+EPSF);
    lx = lane ? acoshf(th)*t/yn : 0.f;
  }
  float mv = 0.f;
  #pragma unroll
  for(int k = 0; k < 64; k++){
    mv = fmaf(__shfl(lx, k), Wt[k*65 + lane], mv);
  }
  float u  = lane ? mv : 0.f;
  float s  = wredsum(u*u);
  float un = fmaxf(sqrtf(s), MINN);
  float sc = sinhf(un)/un;
  float e  = sc*u;
  float s2 = wredsum(e*e);
  float r0 = sqrtf(fmaxf(1.f+s2, EPSF));
  float ubt   = lane ? ub[lane] : 0.f;
  float yn    = fmaxf(sqrtf(s2), MINN);
  float yhat  = e/yn;
  float alpha = wredsum(yhat*ubt);
  float w     = ubt - alpha*(1.f - r0)*yhat;
  float ux    = wredsum(e*w);
  float v0    = ux / fmaxf(r0, EPSF);
  float md    = wredsum(w*w) - v0*v0;
  float normu = fminf(sqrtf(fmaxf(md, EPSF)), MAXN);
  float th2   = fmaxf(normu, MINN);
  float ch    = coshf(th2);
  float shq   = sinhf(th2)/th2;
  float ov    = ch*(lane ? e : r0) + shq*(lane ? w : v0);
  float ot    = lane ? ov : 0.f;
  float s3    = wredsum(ot*ot);
  float o0    = sqrtf(fmaxf(1.f+s3, EPSF));
  float yn2 = fmaxf(sqrtf(s3), MINN);
  float th3 = fmaxf(o0, 1.f+EPSF);
  float gv  = lane ? acoshf(th3)*ot/yn2 : 0.f;
  g[(size_t)row*64 + lane] = gv;
}

// ---- transpose + fp8 convert: g[N][64] f32 -> gF8T[64][N] fp8
__global__ __launch_bounds__(256) void k_trf8(const float* __restrict__ g,
                                              uint* __restrict__ gF8T){
  __shared__ float t[64][65];
  int tid = threadIdx.x;
  int b   = blockIdx.x;
  int r   = tid >> 2;
  int c0  = (tid & 3)*16;
  const float* src = g + ((size_t)b*64 + r)*64 + c0;
  #pragma unroll
  for(int i = 0; i < 4; i++){
    float4 v = *(const float4*)(src + i*4);
    t[r][c0 + i*4 + 0] = v.x; t[r][c0 + i*4 + 1] = v.y;
    t[r][c0 + i*4 + 2] = v.z; t[r][c0 + i*4 + 3] = v.w;
  }
  __syncthreads();
  int n   = tid >> 2;
  int seg = tid & 3;
  int s16 = seg*16;
  uint4 p;
  p.x = __builtin_amdgcn_cvt_pk_fp8_f32(t[s16+ 0][n], t[s16+ 1][n], 0u, false);
  p.x = __builtin_amdgcn_cvt_pk_fp8_f32(t[s16+ 2][n], t[s16+ 3][n], p.x, true);
  p.y = __builtin_amdgcn_cvt_pk_fp8_f32(t[s16+ 4][n], t[s16+ 5][n], 0u, false);
  p.y = __builtin_amdgcn_cvt_pk_fp8_f32(t[s16+ 6][n], t[s16+ 7][n], p.y, true);
  p.z = __builtin_amdgcn_cvt_pk_fp8_f32(t[s16+ 8][n], t[s16+ 9][n], 0u, false);
  p.z = __builtin_amdgcn_cvt_pk_fp8_f32(t[s16+10][n], t[s16+11][n], p.z, true);
  p.w = __builtin_amdgcn_cvt_pk_fp8_f32(t[s16+12][n], t[s16+13][n], 0u, false);
  p.w = __builtin_amdgcn_cvt_pk_fp8_f32(t[s16+14][n], t[s16+15][n], p.w, true);
  uint4* dst = (uint4*)gF8T + (size_t)n*(KDIM/16) + b*4 + seg;
  *dst = p;
}

// ---- fp8 32x32x16 MFMA split-K matmul: A and B both LDS-staged (dbuf, 1 barrier/step)
__global__ __launch_bounds__(256) void k_matmul(const unsigned char* __restrict__ adjF8,
                                                const unsigned char* __restrict__ gF8T,
                                                float* __restrict__ pagg){
  __shared__ __align__(16) char Alds[2*ABUF];   // 8.4 KB
  __shared__ __align__(16) char Blds[2*BBUF];   // 8.3 KB
  int tid  = threadIdx.x;
  int lane = tid & 63, w = tid >> 6;
  int rb   = blockIdx.x;               // rb in LOW grid bits
  int ks   = blockIdx.y;
  int row0 = rb*BM;
  size_t k0 = (size_t)ks * KRANGE;

  // A staging: thread -> (row sr, 16B k-seg sseg); coalesced uint4
  int sr   = tid >> 2;                 // 0..63
  int sseg = tid & 3;                  // 0..3
  const uint4* ap = (const uint4*)(adjF8 + (size_t)(row0 + sr)*KDIM + k0 + sseg*16);
  int AwOff0 = (2*sseg    )*APGS + sr*8;
  int AwOff1 = (2*sseg + 1)*APGS + sr*8;

  // B staging: thread -> (col sc, 16B k-seg skq); 64B full-line granule per col
  int sc  = tid >> 2;                  // 0..63 (col)
  int skq = tid & 3;                   // 0..3
  const uint4* bsp = (const uint4*)(gF8T + (size_t)sc*KDIM + k0 + skq*16);
  int BwOff0 = (2*skq    )*BPGS + sc*8;
  int BwOff1 = (2*skq + 1)*BPGS + sc*8;

  // compute role: wave (wm,wn) -> rows wm*32..+32, cols wn*32..+32
  int wm = w >> 1, wn = w & 1;
  int lr = lane & 31, lh = lane >> 5;
  int ArdOff = lh*APGS + (wm*32 + lr)*8;         // chunk m adds 2m*APGS
  int BrdOff = lh*BPGS + (wn*32 + lr)*8;         // chunk m adds 2m*BPGS

  f32x16 acc;
  #pragma unroll
  for(int q = 0; q < 16; q++) acc[q] = 0.f;

  uint4 aR, aN, bR, bN;

  // prologue: stage step 0; preload step 1
  aR = ap[0];
  bR = bsp[0];
  {
    union { uint4 v; u64 q[2]; } ua; ua.v = aR;
    *(u64*)(Alds + AwOff0) = ua.q[0];
    *(u64*)(Alds + AwOff1) = ua.q[1];
    union { uint4 v; u64 q[2]; } ub_; ub_.v = bR;
    *(u64*)(Blds + BwOff0) = ub_.q[0];
    *(u64*)(Blds + BwOff1) = ub_.q[1];
  }
  aR = ap[4];                                    // step stride = 4 uint4 (64B)
  bR = bsp[4];
  __syncthreads();

  for (int i = 0; i < NSTEP; i++){
    const char* Ab = Alds + (i & 1)*ABUF;
    const char* Bb = Blds + (i & 1)*BBUF;
    i64 af0 = *(const i64*)(Ab + ArdOff);
    i64 af1 = *(const i64*)(Ab + ArdOff + 2*APGS);
    i64 af2 = *(const i64*)(Ab + ArdOff + 4*APGS);
    i64 af3 = *(const i64*)(Ab + ArdOff + 6*APGS);
    i64 bf0 = *(const i64*)(Bb + BrdOff);
    i64 bf1 = *(const i64*)(Bb + BrdOff + 2*BPGS);
    i64 bf2 = *(const i64*)(Bb + BrdOff + 4*BPGS);
    i64 bf3 = *(const i64*)(Bb + BrdOff + 6*BPGS);
    if (i + 2 < NSTEP){
      aN = ap[(i+2)*4];
      bN = bsp[(i+2)*4];
    }
    acc = __builtin_amdgcn_mfma_f32_32x32x16_fp8_fp8(af0, bf0, acc, 0, 0, 0);
    acc = __builtin_amdgcn_mfma_f32_32x32x16_fp8_fp8(af1, bf1, acc, 0, 0, 0);
    acc = __builtin_amdgcn_mfma_f32_32x32x16_fp8_fp8(af2, bf2, acc, 0, 0, 0);
    acc = __builtin_amdgcn_mfma_f32_32x32x16_fp8_fp8(af3, bf3, acc, 0, 0, 0);
    if (i + 1 < NSTEP){
      char* Aw = Alds + ((i+1) & 1)*ABUF;
      char* Bw = Blds + ((i+1) & 1)*BBUF;
      union { uint4 v; u64 q[2]; } ua; ua.v = aR;
      *(u64*)(Aw + AwOff0) = ua.q[0];
      *(u64*)(Aw + AwOff1) = ua.q[1];
      union { uint4 v; u64 q[2]; } ub_; ub_.v = bR;
      *(u64*)(Bw + BwOff0) = ub_.q[0];
      *(u64*)(Bw + BwOff1) = ub_.q[1];
    }
    aR = aN; bR = bN;
    __syncthreads();
  }

  // C write: 32x32 D layout (m74): col = lane&31, row = (q&3) + 8*(q>>2) + 4*(lane>>5)
  float* ob = pagg + ((size_t)ks*NROWS + row0 + wm*32)*64 + wn*32;
  #pragma unroll
  for(int q = 0; q < 16; q++){
    int rl = (q & 3) + 8*(q >> 2) + 4*lh;
    ob[(size_t)rl*64 + lr] = acc[q];
  }
}

// ---- fused: split-K reduce + postagg chain -> h (rinv precomputed by k_cvt)
__global__ __launch_bounds__(256) void k_post(const float* __restrict__ pagg,
                                              const float* __restrict__ rinv,
                                              float* __restrict__ h){
  int tid = threadIdx.x; int lane = tid & 63;
  int row = blockIdx.x*4 + (tid >> 6);
  float s = 0.f;
  #pragma unroll
  for(int ks = 0; ks < KSPLIT; ks++) s += pagg[(size_t)ks*NROWS*64 + (size_t)row*64 + lane];
  float a  = s * rinv[row];
  float at = lane ? a : 0.f;
  float ss = wredsum(at*at);
  float un = fmaxf(sqrtf(ss), MINN);
  float sc = sinhf(un)/un;
  float e  = sc*at;
  float s2 = wredsum(e*e);
  float x0 = sqrtf(fmaxf(1.f+s2, EPSF));
  float yn = fmaxf(sqrtf(s2), MINN);
  float th = fmaxf(x0, 1.f+EPSF);
  float lt = lane ? acoshf(th)*e/yn : 0.f;
  float rl = fmaxf(lt, 0.f);
  float s3 = wredsum(rl*rl);
  float rn = fmaxf(sqrtf(s3), MINN);
  float sc2= sinhf(rn)/rn;
  float e2 = sc2*rl;
  float s4 = wredsum(e2*e2);
  float h0 = sqrtf(fmaxf(1.f+s4, EPSF));
  h[(size_t)row*64 + lane] = lane ? e2 : h0;
}

extern "C" void kernel_launch(void* const* d_in, const int* in_sizes, int n_in,
                              void* d_out, int out_size, void* d_ws, size_t ws_size,
                              hipStream_t stream){
  const float* x   = (const float*)d_in[0];
  const float* adj = (const float*)d_in[1];
  const float* W1  = (const float*)d_in[2];
  const float* b1  = (const float*)d_in[3];
  const float* W2  = (const float*)d_in[4];
  const float* b2  = (const float*)d_in[5];
  float* out = (float*)d_out;
  float* h1  = out;
  float* h2  = out + (size_t)NROWS*64;

  float* wsf   = (float*)d_ws;
  float* gbuf  = wsf;                              // N*64 f32 (4 MB)
  float* pagg  = gbuf  + (size_t)NROWS*64;         // KSPLIT*N*64 f32 (33.5 MB)
  float* rinv  = pagg  + (size_t)KSPLIT*NROWS*64;  // N
  float* ubs   = rinv  + NROWS;                    // 128
  uint*  gF8T  = (uint*)(ubs + 128);               // 64*N fp8 (1 MB)
  uint*  adjF8 = gF8T + (size_t)64*KDIM/4;         // N*N fp8 (256 MiB)

  dim3 gm(NROWS/BM, KSPLIT);                       // rb in LOW bits

  k_bias<<<1, 128, 0, stream>>>(b1, b2, ubs);
  k_cvt<<<NROWS/4, 256, 0, stream>>>(adj, adjF8, rinv);
  // layer 1
  k_linear<0><<<NROWS/4, 256, 0, stream>>>(x, W1, ubs, gbuf);
  k_trf8<<<NROWS/64, 256, 0, stream>>>(gbuf, gF8T);
  k_matmul<<<gm, 256, 0, stream>>>((const unsigned char*)adjF8, (const unsigned char*)gF8T, pagg);
  k_post<<<NROWS/4, 256, 0, stream>>>(pagg, rinv, h1);
  // layer 2
  k_linear<1><<<NROWS/4, 256, 0, stream>>>(h1, W2, ubs + 64, gbuf);
  k_trf8<<<NROWS/64, 256, 0, stream>>>(gbuf, gF8T);
  k_matmul<<<gm, 256, 0, stream>>>((const unsigned char*)adjF8, (const unsigned char*)gF8T, pagg);
  k_post<<<NROWS/4, 256, 0, stream>>>(pagg, rinv, h2);
}